// Round 2
// baseline (1258.635 us; speedup 1.0000x reference)
//
#include <hip/hip_runtime.h>
#include <cstdint>

#define DV 2048
#define HH 16
#define DHD 128
#define LL 512
#define BB 2

typedef __attribute__((ext_vector_type(8))) short bf16x8;
typedef __attribute__((ext_vector_type(4))) float f32x4;
typedef __attribute__((ext_vector_type(4))) int i32x4;

__device__ __forceinline__ unsigned short f2b(float f) {
    union { float f; unsigned int u; } v; v.f = f;
    unsigned int u = v.u;
    return (unsigned short)((u + 0x7FFFu + ((u >> 16) & 1u)) >> 16);
}

// ---------------- elementwise f32 -> bf16 ----------------
__global__ void cvt_k(const float* __restrict__ in, ushort* __restrict__ out, long n) {
    long stride = (long)gridDim.x * blockDim.x * 4;
    for (long i = ((long)blockIdx.x * blockDim.x + threadIdx.x) * 4; i < n; i += stride) {
        float4 f = *(const float4*)(in + i);
        *(ushort4*)(out + i) = make_ushort4(f2b(f.x), f2b(f.y), f2b(f.z), f2b(f.w));
    }
}

// ---------------- transpose + convert: out[c][r] = in[r][c] ----------------
__global__ void transpose_cvt_k(const float* __restrict__ in, ushort* __restrict__ outp,
                                int R, int C) {
    __shared__ float tile[64][65];
    int c0 = blockIdx.x * 64, r0 = blockIdx.y * 64;
    int tx = threadIdx.x & 63, ty = threadIdx.x >> 6;
#pragma unroll
    for (int p = 0; p < 16; ++p)
        tile[ty + p * 4][tx] = in[(long)(r0 + ty + p * 4) * C + c0 + tx];
    __syncthreads();
#pragma unroll
    for (int p = 0; p < 16; ++p)
        outp[(long)(c0 + ty + p * 4) * R + r0 + tx] = f2b(tile[tx][ty + p * 4]);
}

// ---------------- kv_cache -> c_kv out (f32) + bf16 copy ----------------
__global__ void kvcopy_k(const float* __restrict__ kv, float* __restrict__ cko,
                         ushort* __restrict__ ckb, int PAST, int T) {
    long n = (long)BB * PAST * LL;
    long pl2 = (long)PAST * LL;
    long stride = (long)gridDim.x * blockDim.x * 4;
    for (long i = ((long)blockIdx.x * blockDim.x + threadIdx.x) * 4; i < n; i += stride) {
        float4 f = *(const float4*)(kv + i);
        long b = i / pl2, wloc = i - b * pl2;
        long o = b * (long)T * LL + wloc;
        *(float4*)(cko + o) = f;
        *(ushort4*)(ckb + o) = make_ushort4(f2b(f.x), f2b(f.y), f2b(f.z), f2b(f.w));
    }
}

// ---------------- LayerNorm over L=512, one wave per row ----------------
__global__ __launch_bounds__(256) void ln_k(const float* __restrict__ cpre,
                                            const float* __restrict__ g, const float* __restrict__ be,
                                            float* __restrict__ cko, ushort* __restrict__ ckb,
                                            int S, int PAST, int T) {
    int wid = threadIdx.x >> 6, lane = threadIdx.x & 63;
    int row = blockIdx.x * 4 + wid;
    int b = row / S, s = row - b * S;
    const float* xr = cpre + (long)row * LL + lane * 8;
    float4 v0 = *(const float4*)xr;
    float4 v1 = *(const float4*)(xr + 4);
    float sum = v0.x + v0.y + v0.z + v0.w + v1.x + v1.y + v1.z + v1.w;
    float sq = v0.x * v0.x + v0.y * v0.y + v0.z * v0.z + v0.w * v0.w +
               v1.x * v1.x + v1.y * v1.y + v1.z * v1.z + v1.w * v1.w;
#pragma unroll
    for (int m = 1; m < 64; m <<= 1) { sum += __shfl_xor(sum, m, 64); sq += __shfl_xor(sq, m, 64); }
    float mu = sum * (1.0f / LL);
    float var = sq * (1.0f / LL) - mu * mu;
    float rstd = rsqrtf(var + 1e-5f);
    const float* gp = g + lane * 8;
    const float* bp = be + lane * 8;
    float4 g0 = *(const float4*)gp, g1 = *(const float4*)(gp + 4);
    float4 b0 = *(const float4*)bp, b1 = *(const float4*)(bp + 4);
    float y0 = (v0.x - mu) * rstd * g0.x + b0.x;
    float y1 = (v0.y - mu) * rstd * g0.y + b0.y;
    float y2 = (v0.z - mu) * rstd * g0.z + b0.z;
    float y3 = (v0.w - mu) * rstd * g0.w + b0.w;
    float y4 = (v1.x - mu) * rstd * g1.x + b1.x;
    float y5 = (v1.y - mu) * rstd * g1.y + b1.y;
    float y6 = (v1.z - mu) * rstd * g1.z + b1.z;
    float y7 = (v1.w - mu) * rstd * g1.w + b1.w;
    long o = ((long)b * T + PAST + s) * LL + lane * 8;
    *(float4*)(cko + o) = make_float4(y0, y1, y2, y3);
    *(float4*)(cko + o + 4) = make_float4(y4, y5, y6, y7);
    *(ushort4*)(ckb + o) = make_ushort4(f2b(y0), f2b(y1), f2b(y2), f2b(y3));
    *(ushort4*)(ckb + o + 4) = make_ushort4(f2b(y4), f2b(y5), f2b(y6), f2b(y7));
}

// ---------------- generic NT GEMM: C[M,N] = cscale * A[M,K] * B[N,K]^T ----------------
template <bool OUT_BF16>
__global__ __launch_bounds__(256, 2) void gemm_nt(const ushort* __restrict__ A,
                                                  const ushort* __restrict__ B,
                                                  void* __restrict__ Cv,
                                                  int K, int lda, int ldb, int ldc,
                                                  long aHi, long aLo, long bHi, long bLo,
                                                  long cHi, long cLo, int zdiv, float cscale) {
    __shared__ __align__(16) ushort Asm[128 * 72];
    __shared__ __align__(16) ushort Bsm[128 * 72];
    const int tid = threadIdx.x, wid = tid >> 6, lane = tid & 63;
    const int z = blockIdx.z, zh = z / zdiv, zl = z % zdiv;
    A += zh * aHi + zl * aLo;
    B += zh * bHi + zl * bLo;
    const long cOff = zh * cHi + zl * cLo;
    const int m0 = blockIdx.x * 128, n0 = blockIdx.y * 128;
    const int wm = (wid >> 1) * 64, wn = (wid & 1) * 64;
    f32x4 acc[4][4] = {};
    const int l8 = lane & 7;
    const int rowA = wid * 8 + (lane >> 3);
    const ushort* Ag = A + (long)(m0 + rowA) * lda + l8 * 8;
    const ushort* Bg = B + (long)(n0 + rowA) * ldb + l8 * 8;

    i32x4 ra[4], rb[4];
#pragma unroll
    for (int p = 0; p < 4; ++p) {
        ra[p] = *(const i32x4*)(Ag + (long)p * 32 * lda);
        rb[p] = *(const i32x4*)(Bg + (long)p * 32 * ldb);
    }
    for (int kt = 0; kt < K; kt += 64) {
        __syncthreads();
#pragma unroll
        for (int p = 0; p < 4; ++p) {
            *(i32x4*)(Asm + (p * 32 + rowA) * 72 + l8 * 8) = ra[p];
            *(i32x4*)(Bsm + (p * 32 + rowA) * 72 + l8 * 8) = rb[p];
        }
        __syncthreads();
        if (kt + 64 < K) {
#pragma unroll
            for (int p = 0; p < 4; ++p) {
                ra[p] = *(const i32x4*)(Ag + (long)p * 32 * lda + kt + 64);
                rb[p] = *(const i32x4*)(Bg + (long)p * 32 * ldb + kt + 64);
            }
        }
#pragma unroll
        for (int kk = 0; kk < 2; ++kk) {
            const int ko = kk * 32 + ((lane >> 4) << 3);
            bf16x8 af[4], bf[4];
#pragma unroll
            for (int i = 0; i < 4; ++i)
                af[i] = *(const bf16x8*)(Asm + (wm + i * 16 + (lane & 15)) * 72 + ko);
#pragma unroll
            for (int j = 0; j < 4; ++j)
                bf[j] = *(const bf16x8*)(Bsm + (wn + j * 16 + (lane & 15)) * 72 + ko);
#pragma unroll
            for (int i = 0; i < 4; ++i)
#pragma unroll
                for (int j = 0; j < 4; ++j)
                    acc[i][j] = __builtin_amdgcn_mfma_f32_16x16x32_bf16(af[i], bf[j], acc[i][j], 0, 0, 0);
        }
        __syncthreads();
    }
    const int cr = (lane >> 4) * 4, cc = lane & 15;
#pragma unroll
    for (int i = 0; i < 4; ++i) {
#pragma unroll
        for (int r = 0; r < 4; ++r) {
            const long row = m0 + wm + i * 16 + cr + r;
#pragma unroll
            for (int j = 0; j < 4; ++j) {
                const long col = n0 + wn + j * 16 + cc;
                if (OUT_BF16)
                    ((ushort*)Cv)[cOff + row * ldc + col] = f2b(acc[i][j][r] * cscale);
                else
                    ((float*)Cv)[cOff + row * ldc + col] = acc[i][j][r] * cscale;
            }
        }
    }
}

// ---------------- flash attention (round 2) ----------------
// 4 waves x 16 q-rows = 64 q-rows/block. KV tile 64, L streamed in 128-chunks
// through a double-buffered LDS tile; ONE barrier per chunk. V read directly
// from L2 (no staging). P via wave-private LDS (no barrier).
__global__ __launch_bounds__(256, 3) void attn_k(const ushort* __restrict__ tmpb,
                                                 const ushort* __restrict__ ckvb,
                                                 const ushort* __restrict__ vtb,
                                                 ushort* __restrict__ ctxb,
                                                 int S, int T, int PAST) {
    __shared__ __align__(16) ushort ck[2][64][136];  // double-buffered K chunk [t][128+8pad]
    __shared__ __align__(16) ushort pl[4][16][72];   // per-wave P [q16][t64+8pad]
    const int tid = threadIdx.x, wid = tid >> 6, lane = tid & 63;

    // XCD-aware remap + longest-first: id&7 = XCD; b pinned to XCD half.
    const int nsb = S >> 6;
    const int id = blockIdx.x;
    const int xcd = id & 7, ixc = id >> 3;
    const int b = xcd >> 2;
    const int h = (xcd & 3) * 4 + (ixc & 3);
    const int s0 = (nsb - 1 - (ixc >> 2)) * 64;

    // Q fragments: 16 rows x L=512 per wave, in registers (64 VGPR)
    bf16x8 qf[16];
    {
        const ushort* qb = tmpb + ((long)(b * HH + h) * S + s0 + wid * 16 + (lane & 15)) * LL +
                           ((lane >> 4) << 3);
#pragma unroll
        for (int ks = 0; ks < 16; ++ks) qf[ks] = *(const bf16x8*)(qb + ks * 32);
    }
    f32x4 cacc[8] = {};
    float mrow[4] = {-1e30f, -1e30f, -1e30f, -1e30f};
    float lrow[4] = {0.f, 0.f, 0.f, 0.f};
    const int rl = tid >> 4, cc16 = tid & 15;
    const int q8 = (lane >> 4) << 3;
    const int nfull = (s0 + PAST) / 64;
    const int NG = (nfull + 1) * 4;  // total L-chunks across all KV tiles
    const ushort* kbase = ckvb + (long)b * T * LL;
    const ushort* vp = vtb + ((long)b * DV + h * DHD + (lane & 15)) * T + q8;

    // prologue: stage chunk 0 into buf 0
    i32x4 rc[4];
#pragma unroll
    for (int p = 0; p < 4; ++p)
        rc[p] = *(const i32x4*)(kbase + (long)(p * 16 + rl) * LL + cc16 * 8);
#pragma unroll
    for (int p = 0; p < 4; ++p) *(i32x4*)(&ck[0][p * 16 + rl][cc16 * 8]) = rc[p];
    __syncthreads();

    f32x4 sacc[4] = {};
    for (int g = 0; g < NG; ++g) {
        const int c = g & 3;
        const int cur = g & 1;
        // issue global loads for chunk g+1 (latency hidden under this step)
        if (g + 1 < NG) {
            const int t1 = ((g + 1) >> 2) * 64, c1 = ((g + 1) & 3) * 128;
            const ushort* src = kbase + (long)t1 * LL + c1 + cc16 * 8;
#pragma unroll
            for (int p = 0; p < 4; ++p)
                rc[p] = *(const i32x4*)(src + (long)(p * 16 + rl) * LL);
        }
        // QK^T on chunk g
#pragma unroll
        for (int kk = 0; kk < 4; ++kk) {
            bf16x8 a = qf[c * 4 + kk];
            const int ko = kk * 32 + q8;
#pragma unroll
            for (int nf = 0; nf < 4; ++nf) {
                bf16x8 bfr = *(const bf16x8*)(&ck[cur][nf * 16 + (lane & 15)][ko]);
                sacc[nf] = __builtin_amdgcn_mfma_f32_16x16x32_bf16(a, bfr, sacc[nf], 0, 0, 0);
            }
        }
        if (c == 3) {
            const int tt = g >> 2;
            const int t0 = tt * 64;
            const bool partial = (tt == nfull);
            // ---- online softmax (scores pre-scaled in tmp GEMM) ----
            float pm[4] = {-1e30f, -1e30f, -1e30f, -1e30f};
#pragma unroll
            for (int nf = 0; nf < 4; ++nf)
#pragma unroll
                for (int r = 0; r < 4; ++r) {
                    float v = sacc[nf][r];
                    if (partial) {
                        int tcol = nf * 16 + (lane & 15);
                        int qrl = wid * 16 + ((lane >> 4) << 2) + r;
                        if (tcol > qrl) v = -1e30f;
                    }
                    sacc[nf][r] = v;
                    pm[r] = fmaxf(pm[r], v);
                }
#pragma unroll
            for (int r = 0; r < 4; ++r)
#pragma unroll
                for (int m = 1; m < 16; m <<= 1) pm[r] = fmaxf(pm[r], __shfl_xor(pm[r], m, 64));
            // defer-max (T13): only rescale when max grew by > 8
            bool need = false;
#pragma unroll
            for (int r = 0; r < 4; ++r) need |= (pm[r] > mrow[r] + 8.0f);
            if (__any(need)) {
#pragma unroll
                for (int r = 0; r < 4; ++r) {
                    float mn = fmaxf(mrow[r], pm[r]);
                    float al = __expf(mrow[r] - mn);
                    mrow[r] = mn;
                    lrow[r] *= al;
#pragma unroll
                    for (int df = 0; df < 8; ++df) cacc[df][r] *= al;
                }
            }
            float ps[4] = {0.f, 0.f, 0.f, 0.f};
#pragma unroll
            for (int nf = 0; nf < 4; ++nf)
#pragma unroll
                for (int r = 0; r < 4; ++r) {
                    float p = __expf(sacc[nf][r] - mrow[r]);
                    sacc[nf][r] = p;
                    ps[r] += p;
                }
#pragma unroll
            for (int r = 0; r < 4; ++r) {
#pragma unroll
                for (int m = 1; m < 16; m <<= 1) ps[r] += __shfl_xor(ps[r], m, 64);
                lrow[r] += ps[r];
            }
            // P -> wave-private LDS (no block barrier needed)
#pragma unroll
            for (int nf = 0; nf < 4; ++nf)
#pragma unroll
                for (int r = 0; r < 4; ++r)
                    pl[wid][((lane >> 4) << 2) + r][nf * 16 + (lane & 15)] = f2b(sacc[nf][r]);
#pragma unroll
            for (int nf = 0; nf < 4; ++nf) sacc[nf] = (f32x4){0.f, 0.f, 0.f, 0.f};
            // ---- ctx += P * V ; V B-fragments straight from L2 ----
#pragma unroll
            for (int kk = 0; kk < 2; ++kk) {
                bf16x8 a = *(const bf16x8*)(&pl[wid][lane & 15][kk * 32 + q8]);
#pragma unroll
                for (int df = 0; df < 8; ++df) {
                    bf16x8 bv = *(const bf16x8*)(vp + (long)df * 16 * T + t0 + kk * 32);
                    cacc[df] = __builtin_amdgcn_mfma_f32_16x16x32_bf16(a, bv, cacc[df], 0, 0, 0);
                }
            }
        }
        // publish chunk g+1 into the other buffer, then one barrier
        if (g + 1 < NG) {
#pragma unroll
            for (int p = 0; p < 4; ++p) *(i32x4*)(&ck[cur ^ 1][p * 16 + rl][cc16 * 8]) = rc[p];
        }
        __syncthreads();
    }
    // ---- epilogue ----
    const long rbase = (long)b * S + s0 + wid * 16 + ((lane >> 4) << 2);
#pragma unroll
    for (int r = 0; r < 4; ++r) {
        float inv = 1.0f / lrow[r];
        const int d = h * DHD + (lane & 15);
#pragma unroll
        for (int df = 0; df < 8; ++df)
            ctxb[(rbase + r) * DV + d + df * 16] = f2b(cacc[df][r] * inv);
    }
}

extern "C" void kernel_launch(void* const* d_in, const int* in_sizes, int n_in,
                              void* d_out, int out_size, void* d_ws, size_t ws_size,
                              hipStream_t stream) {
    const float* x = (const float*)d_in[0];
    const float* kv = (const float*)d_in[1];
    const float* Wq = (const float*)d_in[2];
    const float* Wdkv = (const float*)d_in[3];
    const float* Wuk = (const float*)d_in[4];
    const float* Wuv = (const float*)d_in[5];
    const float* Wo = (const float*)d_in[6];
    const float* lng = (const float*)d_in[7];
    const float* lnbt = (const float*)d_in[8];
    const int S = in_sizes[0] / (BB * DV);     // 2048
    const int PAST = in_sizes[1] / (BB * LL);  // 2048
    const int T = S + PAST;                    // 4096

    float* out_p = (float*)d_out;                       // [B,S,D] f32
    float* ckv_out = out_p + (size_t)BB * S * DV;       // [B,T,L] f32

    char* w = (char*)d_ws;
    auto take = [&](size_t bytes) { char* p = w; w += (bytes + 255) & ~(size_t)255; return p; };
    ushort* xb    = (ushort*)take((size_t)BB * S * DV * 2);
    ushort* Wqb   = (ushort*)take((size_t)DV * DV * 2);
    ushort* WukT  = (ushort*)take((size_t)DV * LL * 2);   // [L][D]
    ushort* Wdkvb = (ushort*)take((size_t)LL * DV * 2);
    ushort* Wuvb  = (ushort*)take((size_t)DV * LL * 2);
    ushort* Wob   = (ushort*)take((size_t)DV * DV * 2);
    ushort* absT  = (ushort*)take((size_t)LL * DV * 2);   // [L][D] = absorbed^T
    float*  cpre  = (float*)take((size_t)BB * S * LL * 4);
    ushort* ckvb  = (ushort*)take((size_t)BB * T * LL * 2);
    ushort* vtb   = (ushort*)take((size_t)BB * DV * T * 2); // [B][D][T]
    ushort* tmpb  = (ushort*)take((size_t)BB * HH * S * LL * 2);
    ushort* ctxb  = (ushort*)take((size_t)BB * S * DV * 2);

    auto cvt = [&](const float* in, ushort* op, long n) {
        long nb = (n / 4 + 255) / 256;
        if (nb > 2048) nb = 2048;
        cvt_k<<<dim3((unsigned)nb), dim3(256), 0, stream>>>(in, op, n);
    };
    cvt(x, xb, (long)BB * S * DV);
    cvt(Wq, Wqb, (long)DV * DV);
    cvt(Wdkv, Wdkvb, (long)LL * DV);
    cvt(Wuv, Wuvb, (long)DV * LL);
    cvt(Wo, Wob, (long)DV * DV);
    transpose_cvt_k<<<dim3(LL / 64, DV / 64), dim3(256), 0, stream>>>(Wuk, WukT, DV, LL);
    kvcopy_k<<<dim3(2048), dim3(256), 0, stream>>>(kv, ckv_out, ckvb, PAST, T);

    // absorbed^T[l,i] = sum_k WukT[l,k] * Wq[i,k]
    gemm_nt<true><<<dim3(LL / 128, DV / 128, 1), dim3(256), 0, stream>>>(
        WukT, Wqb, absT, DV, DV, DV, DV, 0, 0, 0, 0, 0, 0, 1, 1.0f);
    // c_pre = x * Wdkv^T  (f32)
    gemm_nt<false><<<dim3(BB * S / 128, LL / 128, 1), dim3(256), 0, stream>>>(
        xb, Wdkvb, cpre, DV, DV, DV, LL, 0, 0, 0, 0, 0, 0, 1, 1.0f);
    ln_k<<<dim3(BB * S / 4), dim3(256), 0, stream>>>(cpre, lng, lnbt, ckv_out, ckvb, S, PAST, T);
    // Vt[b] = Wuv * ckv[b]^T : [D][T] bf16
    gemm_nt<true><<<dim3(DV / 128, T / 128, BB), dim3(256), 0, stream>>>(
        Wuvb, ckvb, vtb, LL, LL, LL, T, 0, 0, (long)T * LL, 0, (long)DV * T, 0, 1, 1.0f);
    // tmp[b,h] = x_h * absorbed_h^T, pre-scaled by 1/sqrt(dh)
    gemm_nt<true><<<dim3(S / 128, LL / 128, BB * HH), dim3(256), 0, stream>>>(
        xb, absT, tmpb, DHD, DV, DV, LL,
        (long)S * DV, DHD, 0, DHD, (long)HH * S * LL, (long)S * LL, HH,
        0.08838834764831845f);
    // attention
    attn_k<<<dim3(BB * HH * (S / 64)), dim3(256), 0, stream>>>(tmpb, ckvb, vtb, ctxb, S, T, PAST);
    // out = ctx * Wo^T (f32)
    gemm_nt<false><<<dim3(BB * S / 128, DV / 128, 1), dim3(256), 0, stream>>>(
        ctxb, Wob, out_p, DV, DV, DV, DV, 0, 0, 0, 0, 0, 0, 1, 1.0f);
}

// Round 3
// 869.138 us; speedup vs baseline: 1.4481x; 1.4481x over previous
//
#include <hip/hip_runtime.h>
#include <cstdint>

#define DV 2048
#define HH 16
#define DHD 128
#define LL 512
#define BB 2

typedef __attribute__((ext_vector_type(8))) short bf16x8;
typedef __attribute__((ext_vector_type(4))) float f32x4;
typedef __attribute__((ext_vector_type(4))) int i32x4;

__device__ __forceinline__ unsigned short f2b(float f) {
    union { float f; unsigned int u; } v; v.f = f;
    unsigned int u = v.u;
    return (unsigned short)((u + 0x7FFFu + ((u >> 16) & 1u)) >> 16);
}

// ---------------- elementwise f32 -> bf16 ----------------
__global__ void cvt_k(const float* __restrict__ in, ushort* __restrict__ out, long n) {
    long stride = (long)gridDim.x * blockDim.x * 4;
    for (long i = ((long)blockIdx.x * blockDim.x + threadIdx.x) * 4; i < n; i += stride) {
        float4 f = *(const float4*)(in + i);
        *(ushort4*)(out + i) = make_ushort4(f2b(f.x), f2b(f.y), f2b(f.z), f2b(f.w));
    }
}

// ---------------- transpose + convert: out[c][r] = in[r][c] ----------------
__global__ void transpose_cvt_k(const float* __restrict__ in, ushort* __restrict__ outp,
                                int R, int C) {
    __shared__ float tile[64][65];
    int c0 = blockIdx.x * 64, r0 = blockIdx.y * 64;
    int tx = threadIdx.x & 63, ty = threadIdx.x >> 6;
#pragma unroll
    for (int p = 0; p < 16; ++p)
        tile[ty + p * 4][tx] = in[(long)(r0 + ty + p * 4) * C + c0 + tx];
    __syncthreads();
#pragma unroll
    for (int p = 0; p < 16; ++p)
        outp[(long)(c0 + ty + p * 4) * R + r0 + tx] = f2b(tile[tx][ty + p * 4]);
}

// ---------------- kv_cache -> c_kv out (f32) + bf16 copy ----------------
__global__ void kvcopy_k(const float* __restrict__ kv, float* __restrict__ cko,
                         ushort* __restrict__ ckb, int PAST, int T) {
    long n = (long)BB * PAST * LL;
    long pl2 = (long)PAST * LL;
    long stride = (long)gridDim.x * blockDim.x * 4;
    for (long i = ((long)blockIdx.x * blockDim.x + threadIdx.x) * 4; i < n; i += stride) {
        float4 f = *(const float4*)(kv + i);
        long b = i / pl2, wloc = i - b * pl2;
        long o = b * (long)T * LL + wloc;
        *(float4*)(cko + o) = f;
        *(ushort4*)(ckb + o) = make_ushort4(f2b(f.x), f2b(f.y), f2b(f.z), f2b(f.w));
    }
}

// ---------------- LayerNorm over L=512, one wave per row ----------------
__global__ __launch_bounds__(256) void ln_k(const float* __restrict__ cpre,
                                            const float* __restrict__ g, const float* __restrict__ be,
                                            float* __restrict__ cko, ushort* __restrict__ ckb,
                                            int S, int PAST, int T) {
    int wid = threadIdx.x >> 6, lane = threadIdx.x & 63;
    int row = blockIdx.x * 4 + wid;
    int b = row / S, s = row - b * S;
    const float* xr = cpre + (long)row * LL + lane * 8;
    float4 v0 = *(const float4*)xr;
    float4 v1 = *(const float4*)(xr + 4);
    float sum = v0.x + v0.y + v0.z + v0.w + v1.x + v1.y + v1.z + v1.w;
    float sq = v0.x * v0.x + v0.y * v0.y + v0.z * v0.z + v0.w * v0.w +
               v1.x * v1.x + v1.y * v1.y + v1.z * v1.z + v1.w * v1.w;
#pragma unroll
    for (int m = 1; m < 64; m <<= 1) { sum += __shfl_xor(sum, m, 64); sq += __shfl_xor(sq, m, 64); }
    float mu = sum * (1.0f / LL);
    float var = sq * (1.0f / LL) - mu * mu;
    float rstd = rsqrtf(var + 1e-5f);
    const float* gp = g + lane * 8;
    const float* bp = be + lane * 8;
    float4 g0 = *(const float4*)gp, g1 = *(const float4*)(gp + 4);
    float4 b0 = *(const float4*)bp, b1 = *(const float4*)(bp + 4);
    float y0 = (v0.x - mu) * rstd * g0.x + b0.x;
    float y1 = (v0.y - mu) * rstd * g0.y + b0.y;
    float y2 = (v0.z - mu) * rstd * g0.z + b0.z;
    float y3 = (v0.w - mu) * rstd * g0.w + b0.w;
    float y4 = (v1.x - mu) * rstd * g1.x + b1.x;
    float y5 = (v1.y - mu) * rstd * g1.y + b1.y;
    float y6 = (v1.z - mu) * rstd * g1.z + b1.z;
    float y7 = (v1.w - mu) * rstd * g1.w + b1.w;
    long o = ((long)b * T + PAST + s) * LL + lane * 8;
    *(float4*)(cko + o) = make_float4(y0, y1, y2, y3);
    *(float4*)(cko + o + 4) = make_float4(y4, y5, y6, y7);
    *(ushort4*)(ckb + o) = make_ushort4(f2b(y0), f2b(y1), f2b(y2), f2b(y3));
    *(ushort4*)(ckb + o + 4) = make_ushort4(f2b(y4), f2b(y5), f2b(y6), f2b(y7));
}

// ---------------- generic NT GEMM: C[M,N] = cscale * A[M,K] * B[N,K]^T ----------------
template <bool OUT_BF16>
__global__ __launch_bounds__(256, 2) void gemm_nt(const ushort* __restrict__ A,
                                                  const ushort* __restrict__ B,
                                                  void* __restrict__ Cv,
                                                  int K, int lda, int ldb, int ldc,
                                                  long aHi, long aLo, long bHi, long bLo,
                                                  long cHi, long cLo, int zdiv, float cscale) {
    __shared__ __align__(16) ushort Asm[128 * 72];
    __shared__ __align__(16) ushort Bsm[128 * 72];
    const int tid = threadIdx.x, wid = tid >> 6, lane = tid & 63;
    const int z = blockIdx.z, zh = z / zdiv, zl = z % zdiv;
    A += zh * aHi + zl * aLo;
    B += zh * bHi + zl * bLo;
    const long cOff = zh * cHi + zl * cLo;
    const int m0 = blockIdx.x * 128, n0 = blockIdx.y * 128;
    const int wm = (wid >> 1) * 64, wn = (wid & 1) * 64;
    f32x4 acc[4][4] = {};
    const int l8 = lane & 7;
    const int rowA = wid * 8 + (lane >> 3);
    const ushort* Ag = A + (long)(m0 + rowA) * lda + l8 * 8;
    const ushort* Bg = B + (long)(n0 + rowA) * ldb + l8 * 8;

    i32x4 ra[4], rb[4];
#pragma unroll
    for (int p = 0; p < 4; ++p) {
        ra[p] = *(const i32x4*)(Ag + (long)p * 32 * lda);
        rb[p] = *(const i32x4*)(Bg + (long)p * 32 * ldb);
    }
    for (int kt = 0; kt < K; kt += 64) {
        __syncthreads();
#pragma unroll
        for (int p = 0; p < 4; ++p) {
            *(i32x4*)(Asm + (p * 32 + rowA) * 72 + l8 * 8) = ra[p];
            *(i32x4*)(Bsm + (p * 32 + rowA) * 72 + l8 * 8) = rb[p];
        }
        __syncthreads();
        if (kt + 64 < K) {
#pragma unroll
            for (int p = 0; p < 4; ++p) {
                ra[p] = *(const i32x4*)(Ag + (long)p * 32 * lda + kt + 64);
                rb[p] = *(const i32x4*)(Bg + (long)p * 32 * ldb + kt + 64);
            }
        }
#pragma unroll
        for (int kk = 0; kk < 2; ++kk) {
            const int ko = kk * 32 + ((lane >> 4) << 3);
            bf16x8 af[4], bf[4];
#pragma unroll
            for (int i = 0; i < 4; ++i)
                af[i] = *(const bf16x8*)(Asm + (wm + i * 16 + (lane & 15)) * 72 + ko);
#pragma unroll
            for (int j = 0; j < 4; ++j)
                bf[j] = *(const bf16x8*)(Bsm + (wn + j * 16 + (lane & 15)) * 72 + ko);
#pragma unroll
            for (int i = 0; i < 4; ++i)
#pragma unroll
                for (int j = 0; j < 4; ++j)
                    acc[i][j] = __builtin_amdgcn_mfma_f32_16x16x32_bf16(af[i], bf[j], acc[i][j], 0, 0, 0);
        }
        __syncthreads();
    }
    const int cr = (lane >> 4) * 4, cc = lane & 15;
#pragma unroll
    for (int i = 0; i < 4; ++i) {
#pragma unroll
        for (int r = 0; r < 4; ++r) {
            const long row = m0 + wm + i * 16 + cr + r;
#pragma unroll
            for (int j = 0; j < 4; ++j) {
                const long col = n0 + wn + j * 16 + cc;
                if (OUT_BF16)
                    ((ushort*)Cv)[cOff + row * ldc + col] = f2b(acc[i][j][r] * cscale);
                else
                    ((float*)Cv)[cOff + row * ldc + col] = acc[i][j][r] * cscale;
            }
        }
    }
}

// ---------------- flash attention (round 3) ----------------
// 4 waves x 16 q-rows. 5-phase pipeline per KV tile (4 K-chunks + 1 V stage),
// 2 rotating LDS buffers (union: K-view [64][136], V-view [128][72]),
// exactly ONE barrier per phase. All register-array indices compile-time.
__global__ __launch_bounds__(256, 3) void attn_k(const ushort* __restrict__ tmpb,
                                                 const ushort* __restrict__ ckvb,
                                                 const ushort* __restrict__ vtb,
                                                 ushort* __restrict__ ctxb,
                                                 int S, int T, int PAST) {
    __shared__ __align__(16) ushort buf[2][9216];  // K: row t pitch 136; V: row d pitch 72
    __shared__ __align__(16) ushort pl[4][16][72]; // per-wave P [q16][t64+8pad]
    const int tid = threadIdx.x, wid = tid >> 6, lane = tid & 63;
    const int h = blockIdx.y, b = blockIdx.z;
    const int s0 = ((int)gridDim.x - 1 - (int)blockIdx.x) * 64;  // longest-first

    // Q fragments: 16 x bf16x8 (all indices compile-time below)
    bf16x8 qf[16];
    {
        const ushort* qb = tmpb + ((long)(b * HH + h) * S + s0 + wid * 16 + (lane & 15)) * LL +
                           ((lane >> 4) << 3);
#pragma unroll
        for (int ks = 0; ks < 16; ++ks) qf[ks] = *(const bf16x8*)(qb + ks * 32);
    }
    f32x4 cacc[8] = {};
    f32x4 sacc[4] = {};
    float mrow[4] = {-1e30f, -1e30f, -1e30f, -1e30f};
    float lrow[4] = {0.f, 0.f, 0.f, 0.f};
    const int rl = tid >> 4, cc16 = tid & 15;  // K staging coords
    const int vr = tid >> 3, vc = tid & 7;     // V staging coords
    const int q8 = (lane >> 4) << 3;
    const int l15 = lane & 15;
    const int nfull = (s0 + PAST) / 64;
    const ushort* kbase = ckvb + (long)b * T * LL;
    const ushort* vbase = vtb + ((long)b * DV + h * DHD) * T;

    i32x4 rr[4];  // shared prefetch regs (K or V, never both in flight)
    // prologue: K(tile 0, chunk 0) -> buf[0]
#pragma unroll
    for (int p = 0; p < 4; ++p)
        rr[p] = *(const i32x4*)(kbase + (long)(p * 16 + rl) * LL + cc16 * 8);
#pragma unroll
    for (int p = 0; p < 4; ++p)
        *(i32x4*)(&buf[0][(p * 16 + rl) * 136 + cc16 * 8]) = rr[p];
    __syncthreads();

    int cur = 0;
    for (int tt = 0; tt <= nfull; ++tt) {
        const int t0 = tt * 64;
        const bool partial = (tt == nfull);
#pragma unroll
        for (int c = 0; c < 4; ++c) {
            // issue next phase's loads (K chunk c+1, or V tile for c==3)
            if (c < 3) {
                const ushort* src = kbase + (long)(t0 + rl) * LL + (c + 1) * 128 + cc16 * 8;
#pragma unroll
                for (int p = 0; p < 4; ++p)
                    rr[p] = *(const i32x4*)(src + (long)(p * 16) * LL);
            } else {
#pragma unroll
                for (int p = 0; p < 4; ++p)
                    rr[p] = *(const i32x4*)(vbase + (long)(p * 32 + vr) * T + t0 + vc * 8);
            }
            // QK^T on chunk c from buf[cur]
            __builtin_amdgcn_s_setprio(1);
#pragma unroll
            for (int kk = 0; kk < 4; ++kk) {
                bf16x8 a = qf[c * 4 + kk];
                const int ko = kk * 32 + q8;
#pragma unroll
                for (int nf = 0; nf < 4; ++nf) {
                    bf16x8 bfr = *(const bf16x8*)(&buf[cur][(nf * 16 + l15) * 136 + ko]);
                    sacc[nf] = __builtin_amdgcn_mfma_f32_16x16x32_bf16(a, bfr, sacc[nf], 0, 0, 0);
                }
            }
            __builtin_amdgcn_s_setprio(0);
            // publish prefetched data into the other buffer
            if (c < 3) {
#pragma unroll
                for (int p = 0; p < 4; ++p)
                    *(i32x4*)(&buf[cur ^ 1][(p * 16 + rl) * 136 + cc16 * 8]) = rr[p];
            } else {
#pragma unroll
                for (int p = 0; p < 4; ++p)
                    *(i32x4*)(&buf[cur ^ 1][(p * 32 + vr) * 72 + vc * 8]) = rr[p];
            }
            __syncthreads();
            cur ^= 1;
        }
        // ---- phase 4: prefetch K(tt+1, chunk0); softmax; PV from buf[cur] V-view ----
        if (!partial) {
            const ushort* src = kbase + (long)(t0 + 64 + rl) * LL + cc16 * 8;
#pragma unroll
            for (int p = 0; p < 4; ++p)
                rr[p] = *(const i32x4*)(src + (long)(p * 16) * LL);
        }
        // online softmax (scores pre-scaled in tmp GEMM)
        float pm[4] = {-1e30f, -1e30f, -1e30f, -1e30f};
#pragma unroll
        for (int nf = 0; nf < 4; ++nf)
#pragma unroll
            for (int r = 0; r < 4; ++r) {
                float v = sacc[nf][r];
                if (partial) {
                    int tcol = nf * 16 + l15;
                    int qrl = wid * 16 + ((lane >> 4) << 2) + r;
                    if (tcol > qrl) v = -1e30f;
                }
                sacc[nf][r] = v;
                pm[r] = fmaxf(pm[r], v);
            }
#pragma unroll
        for (int r = 0; r < 4; ++r)
#pragma unroll
            for (int m = 1; m < 16; m <<= 1) pm[r] = fmaxf(pm[r], __shfl_xor(pm[r], m, 64));
        bool need = false;
#pragma unroll
        for (int r = 0; r < 4; ++r) need |= (pm[r] > mrow[r] + 8.0f);
        if (__any(need)) {
#pragma unroll
            for (int r = 0; r < 4; ++r) {
                float mn = fmaxf(mrow[r], pm[r]);
                float al = __expf(mrow[r] - mn);
                mrow[r] = mn;
                lrow[r] *= al;
#pragma unroll
                for (int df = 0; df < 8; ++df) cacc[df][r] *= al;
            }
        }
        float ps[4] = {0.f, 0.f, 0.f, 0.f};
#pragma unroll
        for (int nf = 0; nf < 4; ++nf)
#pragma unroll
            for (int r = 0; r < 4; ++r) {
                float p = __expf(sacc[nf][r] - mrow[r]);
                sacc[nf][r] = p;
                ps[r] += p;
            }
#pragma unroll
        for (int r = 0; r < 4; ++r) {
#pragma unroll
            for (int m = 1; m < 16; m <<= 1) ps[r] += __shfl_xor(ps[r], m, 64);
            lrow[r] += ps[r];
        }
        // P -> wave-private LDS (no block barrier needed)
#pragma unroll
        for (int nf = 0; nf < 4; ++nf)
#pragma unroll
            for (int r = 0; r < 4; ++r)
                pl[wid][((lane >> 4) << 2) + r][nf * 16 + l15] = f2b(sacc[nf][r]);
#pragma unroll
        for (int nf = 0; nf < 4; ++nf) sacc[nf] = (f32x4){0.f, 0.f, 0.f, 0.f};
        // ctx += P * V from staged V tile
        __builtin_amdgcn_s_setprio(1);
#pragma unroll
        for (int kk = 0; kk < 2; ++kk) {
            bf16x8 a = *(const bf16x8*)(&pl[wid][l15][kk * 32 + q8]);
#pragma unroll
            for (int df = 0; df < 8; ++df) {
                bf16x8 bv = *(const bf16x8*)(&buf[cur][(df * 16 + l15) * 72 + kk * 32 + q8]);
                cacc[df] = __builtin_amdgcn_mfma_f32_16x16x32_bf16(a, bv, cacc[df], 0, 0, 0);
            }
        }
        __builtin_amdgcn_s_setprio(0);
        if (!partial) {
#pragma unroll
            for (int p = 0; p < 4; ++p)
                *(i32x4*)(&buf[cur ^ 1][(p * 16 + rl) * 136 + cc16 * 8]) = rr[p];
            __syncthreads();
        }
        cur ^= 1;
    }
    // ---- epilogue ----
    const long rbase = (long)b * S + s0 + wid * 16 + ((lane >> 4) << 2);
#pragma unroll
    for (int r = 0; r < 4; ++r) {
        float inv = 1.0f / lrow[r];
        const int d = h * DHD + l15;
#pragma unroll
        for (int df = 0; df < 8; ++df)
            ctxb[(rbase + r) * DV + d + df * 16] = f2b(cacc[df][r] * inv);
    }
}

extern "C" void kernel_launch(void* const* d_in, const int* in_sizes, int n_in,
                              void* d_out, int out_size, void* d_ws, size_t ws_size,
                              hipStream_t stream) {
    const float* x = (const float*)d_in[0];
    const float* kv = (const float*)d_in[1];
    const float* Wq = (const float*)d_in[2];
    const float* Wdkv = (const float*)d_in[3];
    const float* Wuk = (const float*)d_in[4];
    const float* Wuv = (const float*)d_in[5];
    const float* Wo = (const float*)d_in[6];
    const float* lng = (const float*)d_in[7];
    const float* lnbt = (const float*)d_in[8];
    const int S = in_sizes[0] / (BB * DV);     // 2048
    const int PAST = in_sizes[1] / (BB * LL);  // 2048
    const int T = S + PAST;                    // 4096

    float* out_p = (float*)d_out;                       // [B,S,D] f32
    float* ckv_out = out_p + (size_t)BB * S * DV;       // [B,T,L] f32

    char* w = (char*)d_ws;
    auto take = [&](size_t bytes) { char* p = w; w += (bytes + 255) & ~(size_t)255; return p; };
    ushort* xb    = (ushort*)take((size_t)BB * S * DV * 2);
    ushort* Wqb   = (ushort*)take((size_t)DV * DV * 2);
    ushort* WukT  = (ushort*)take((size_t)DV * LL * 2);   // [L][D]
    ushort* Wdkvb = (ushort*)take((size_t)LL * DV * 2);
    ushort* Wuvb  = (ushort*)take((size_t)DV * LL * 2);
    ushort* Wob   = (ushort*)take((size_t)DV * DV * 2);
    ushort* absT  = (ushort*)take((size_t)LL * DV * 2);   // [L][D] = absorbed^T
    float*  cpre  = (float*)take((size_t)BB * S * LL * 4);
    ushort* ckvb  = (ushort*)take((size_t)BB * T * LL * 2);
    ushort* vtb   = (ushort*)take((size_t)BB * DV * T * 2); // [B][D][T]
    ushort* tmpb  = (ushort*)take((size_t)BB * HH * S * LL * 2);
    ushort* ctxb  = (ushort*)take((size_t)BB * S * DV * 2);

    auto cvt = [&](const float* in, ushort* op, long n) {
        long nb = (n / 4 + 255) / 256;
        if (nb > 2048) nb = 2048;
        cvt_k<<<dim3((unsigned)nb), dim3(256), 0, stream>>>(in, op, n);
    };
    cvt(x, xb, (long)BB * S * DV);
    cvt(Wq, Wqb, (long)DV * DV);
    cvt(Wdkv, Wdkvb, (long)LL * DV);
    cvt(Wuv, Wuvb, (long)DV * LL);
    cvt(Wo, Wob, (long)DV * DV);
    transpose_cvt_k<<<dim3(LL / 64, DV / 64), dim3(256), 0, stream>>>(Wuk, WukT, DV, LL);
    kvcopy_k<<<dim3(2048), dim3(256), 0, stream>>>(kv, ckv_out, ckvb, PAST, T);

    // absorbed^T[l,i] = sum_k WukT[l,k] * Wq[i,k]
    gemm_nt<true><<<dim3(LL / 128, DV / 128, 1), dim3(256), 0, stream>>>(
        WukT, Wqb, absT, DV, DV, DV, DV, 0, 0, 0, 0, 0, 0, 1, 1.0f);
    // c_pre = x * Wdkv^T  (f32)
    gemm_nt<false><<<dim3(BB * S / 128, LL / 128, 1), dim3(256), 0, stream>>>(
        xb, Wdkvb, cpre, DV, DV, DV, LL, 0, 0, 0, 0, 0, 0, 1, 1.0f);
    ln_k<<<dim3(BB * S / 4), dim3(256), 0, stream>>>(cpre, lng, lnbt, ckv_out, ckvb, S, PAST, T);
    // Vt[b] = Wuv * ckv[b]^T : [D][T] bf16
    gemm_nt<true><<<dim3(DV / 128, T / 128, BB), dim3(256), 0, stream>>>(
        Wuvb, ckvb, vtb, LL, LL, LL, T, 0, 0, (long)T * LL, 0, (long)DV * T, 0, 1, 1.0f);
    // tmp[b,h] = x_h * absorbed_h^T, pre-scaled by 1/sqrt(dh)
    gemm_nt<true><<<dim3(S / 128, LL / 128, BB * HH), dim3(256), 0, stream>>>(
        xb, absT, tmpb, DHD, DV, DV, LL,
        (long)S * DV, DHD, 0, DHD, (long)HH * S * LL, (long)S * LL, HH,
        0.08838834764831845f);
    // attention
    attn_k<<<dim3(S / 64, HH, BB), dim3(256), 0, stream>>>(tmpb, ckvb, vtb, ctxb, S, T, PAST);
    // out = ctx * Wo^T (f32)
    gemm_nt<false><<<dim3(BB * S / 128, DV / 128, 1), dim3(256), 0, stream>>>(
        ctxb, Wob, out_p, DV, DV, DV, DV, 0, 0, 0, 0, 0, 0, 1, 1.0f);
}

// Round 4
// 824.077 us; speedup vs baseline: 1.5273x; 1.0547x over previous
//
#include <hip/hip_runtime.h>
#include <cstdint>

#define DV 2048
#define HH 16
#define DHD 128
#define LL 512
#define BB 2

typedef __attribute__((ext_vector_type(8))) short bf16x8;
typedef __attribute__((ext_vector_type(4))) float f32x4;
typedef __attribute__((ext_vector_type(4))) int i32x4;

typedef __attribute__((address_space(1))) const void* gas_cp;
typedef __attribute__((address_space(3))) void* las_p;

__device__ __forceinline__ void gll16(const void* g, void* l) {
    __builtin_amdgcn_global_load_lds((gas_cp)g, (las_p)l, 16, 0, 0);
}

__device__ __forceinline__ unsigned short f2b(float f) {
    union { float f; unsigned int u; } v; v.f = f;
    unsigned int u = v.u;
    return (unsigned short)((u + 0x7FFFu + ((u >> 16) & 1u)) >> 16);
}

// ---------------- elementwise f32 -> bf16 ----------------
__global__ void cvt_k(const float* __restrict__ in, ushort* __restrict__ out, long n) {
    long stride = (long)gridDim.x * blockDim.x * 4;
    for (long i = ((long)blockIdx.x * blockDim.x + threadIdx.x) * 4; i < n; i += stride) {
        float4 f = *(const float4*)(in + i);
        *(ushort4*)(out + i) = make_ushort4(f2b(f.x), f2b(f.y), f2b(f.z), f2b(f.w));
    }
}

// ---------------- transpose + convert: out[c][r] = in[r][c] ----------------
__global__ void transpose_cvt_k(const float* __restrict__ in, ushort* __restrict__ outp,
                                int R, int C) {
    __shared__ float tile[64][65];
    int c0 = blockIdx.x * 64, r0 = blockIdx.y * 64;
    int tx = threadIdx.x & 63, ty = threadIdx.x >> 6;
#pragma unroll
    for (int p = 0; p < 16; ++p)
        tile[ty + p * 4][tx] = in[(long)(r0 + ty + p * 4) * C + c0 + tx];
    __syncthreads();
#pragma unroll
    for (int p = 0; p < 16; ++p)
        outp[(long)(c0 + ty + p * 4) * R + r0 + tx] = f2b(tile[tx][ty + p * 4]);
}

// ---------------- kv_cache -> c_kv out (f32) + bf16 copy ----------------
__global__ void kvcopy_k(const float* __restrict__ kv, float* __restrict__ cko,
                         ushort* __restrict__ ckb, int PAST, int T) {
    long n = (long)BB * PAST * LL;
    long pl2 = (long)PAST * LL;
    long stride = (long)gridDim.x * blockDim.x * 4;
    for (long i = ((long)blockIdx.x * blockDim.x + threadIdx.x) * 4; i < n; i += stride) {
        float4 f = *(const float4*)(kv + i);
        long b = i / pl2, wloc = i - b * pl2;
        long o = b * (long)T * LL + wloc;
        *(float4*)(cko + o) = f;
        *(ushort4*)(ckb + o) = make_ushort4(f2b(f.x), f2b(f.y), f2b(f.z), f2b(f.w));
    }
}

// ---------------- LayerNorm over L=512, one wave per row ----------------
__global__ __launch_bounds__(256) void ln_k(const float* __restrict__ cpre,
                                            const float* __restrict__ g, const float* __restrict__ be,
                                            float* __restrict__ cko, ushort* __restrict__ ckb,
                                            int S, int PAST, int T) {
    int wid = threadIdx.x >> 6, lane = threadIdx.x & 63;
    int row = blockIdx.x * 4 + wid;
    int b = row / S, s = row - b * S;
    const float* xr = cpre + (long)row * LL + lane * 8;
    float4 v0 = *(const float4*)xr;
    float4 v1 = *(const float4*)(xr + 4);
    float sum = v0.x + v0.y + v0.z + v0.w + v1.x + v1.y + v1.z + v1.w;
    float sq = v0.x * v0.x + v0.y * v0.y + v0.z * v0.z + v0.w * v0.w +
               v1.x * v1.x + v1.y * v1.y + v1.z * v1.z + v1.w * v1.w;
#pragma unroll
    for (int m = 1; m < 64; m <<= 1) { sum += __shfl_xor(sum, m, 64); sq += __shfl_xor(sq, m, 64); }
    float mu = sum * (1.0f / LL);
    float var = sq * (1.0f / LL) - mu * mu;
    float rstd = rsqrtf(var + 1e-5f);
    const float* gp = g + lane * 8;
    const float* bp = be + lane * 8;
    float4 g0 = *(const float4*)gp, g1 = *(const float4*)(gp + 4);
    float4 b0 = *(const float4*)bp, b1 = *(const float4*)(bp + 4);
    float y0 = (v0.x - mu) * rstd * g0.x + b0.x;
    float y1 = (v0.y - mu) * rstd * g0.y + b0.y;
    float y2 = (v0.z - mu) * rstd * g0.z + b0.z;
    float y3 = (v0.w - mu) * rstd * g0.w + b0.w;
    float y4 = (v1.x - mu) * rstd * g1.x + b1.x;
    float y5 = (v1.y - mu) * rstd * g1.y + b1.y;
    float y6 = (v1.z - mu) * rstd * g1.z + b1.z;
    float y7 = (v1.w - mu) * rstd * g1.w + b1.w;
    long o = ((long)b * T + PAST + s) * LL + lane * 8;
    *(float4*)(cko + o) = make_float4(y0, y1, y2, y3);
    *(float4*)(cko + o + 4) = make_float4(y4, y5, y6, y7);
    *(ushort4*)(ckb + o) = make_ushort4(f2b(y0), f2b(y1), f2b(y2), f2b(y3));
    *(ushort4*)(ckb + o + 4) = make_ushort4(f2b(y4), f2b(y5), f2b(y6), f2b(y7));
}

// ---------------- generic NT GEMM: C[M,N] = cscale * A[M,K] * B[N,K]^T ----------------
template <bool OUT_BF16>
__global__ __launch_bounds__(256, 2) void gemm_nt(const ushort* __restrict__ A,
                                                  const ushort* __restrict__ B,
                                                  void* __restrict__ Cv,
                                                  int K, int lda, int ldb, int ldc,
                                                  long aHi, long aLo, long bHi, long bLo,
                                                  long cHi, long cLo, int zdiv, float cscale) {
    __shared__ __align__(16) ushort Asm[128 * 72];
    __shared__ __align__(16) ushort Bsm[128 * 72];
    const int tid = threadIdx.x, wid = tid >> 6, lane = tid & 63;
    const int z = blockIdx.z, zh = z / zdiv, zl = z % zdiv;
    A += zh * aHi + zl * aLo;
    B += zh * bHi + zl * bLo;
    const long cOff = zh * cHi + zl * cLo;
    const int m0 = blockIdx.x * 128, n0 = blockIdx.y * 128;
    const int wm = (wid >> 1) * 64, wn = (wid & 1) * 64;
    f32x4 acc[4][4] = {};
    const int l8 = lane & 7;
    const int rowA = wid * 8 + (lane >> 3);
    const ushort* Ag = A + (long)(m0 + rowA) * lda + l8 * 8;
    const ushort* Bg = B + (long)(n0 + rowA) * ldb + l8 * 8;

    i32x4 ra[4], rb[4];
#pragma unroll
    for (int p = 0; p < 4; ++p) {
        ra[p] = *(const i32x4*)(Ag + (long)p * 32 * lda);
        rb[p] = *(const i32x4*)(Bg + (long)p * 32 * ldb);
    }
    for (int kt = 0; kt < K; kt += 64) {
        __syncthreads();
#pragma unroll
        for (int p = 0; p < 4; ++p) {
            *(i32x4*)(Asm + (p * 32 + rowA) * 72 + l8 * 8) = ra[p];
            *(i32x4*)(Bsm + (p * 32 + rowA) * 72 + l8 * 8) = rb[p];
        }
        __syncthreads();
        if (kt + 64 < K) {
#pragma unroll
            for (int p = 0; p < 4; ++p) {
                ra[p] = *(const i32x4*)(Ag + (long)p * 32 * lda + kt + 64);
                rb[p] = *(const i32x4*)(Bg + (long)p * 32 * ldb + kt + 64);
            }
        }
#pragma unroll
        for (int kk = 0; kk < 2; ++kk) {
            const int ko = kk * 32 + ((lane >> 4) << 3);
            bf16x8 af[4], bf[4];
#pragma unroll
            for (int i = 0; i < 4; ++i)
                af[i] = *(const bf16x8*)(Asm + (wm + i * 16 + (lane & 15)) * 72 + ko);
#pragma unroll
            for (int j = 0; j < 4; ++j)
                bf[j] = *(const bf16x8*)(Bsm + (wn + j * 16 + (lane & 15)) * 72 + ko);
#pragma unroll
            for (int i = 0; i < 4; ++i)
#pragma unroll
                for (int j = 0; j < 4; ++j)
                    acc[i][j] = __builtin_amdgcn_mfma_f32_16x16x32_bf16(af[i], bf[j], acc[i][j], 0, 0, 0);
        }
        __syncthreads();
    }
    const int cr = (lane >> 4) * 4, cc = lane & 15;
#pragma unroll
    for (int i = 0; i < 4; ++i) {
#pragma unroll
        for (int r = 0; r < 4; ++r) {
            const long row = m0 + wm + i * 16 + cr + r;
#pragma unroll
            for (int j = 0; j < 4; ++j) {
                const long col = n0 + wn + j * 16 + cc;
                if (OUT_BF16)
                    ((ushort*)Cv)[cOff + row * ldc + col] = f2b(acc[i][j][r] * cscale);
                else
                    ((float*)Cv)[cOff + row * ldc + col] = acc[i][j][r] * cscale;
            }
        }
    }
}

// ---------------- flash attention (round 4) ----------------
// 4 waves x 16 q-rows. 5 phases per KV tile (4 K-chunks + softmax/PV).
// global_load_lds staging (lane-linear LDS dest, XOR-swizzled global source,
// swizzled fragment reads), counted vmcnt(4), raw s_barrier — loads issued
// 2 phases ahead, never drained to 0 in the main loop.
#define ATT_BAR_LG()                                             \
    do {                                                         \
        asm volatile("s_waitcnt lgkmcnt(0)" ::: "memory");       \
        __builtin_amdgcn_s_barrier();                            \
        __builtin_amdgcn_sched_barrier(0);                       \
    } while (0)
#define ATT_BAR_VM4()                                            \
    do {                                                         \
        asm volatile("s_waitcnt vmcnt(4)" ::: "memory");         \
        __builtin_amdgcn_s_barrier();                            \
        __builtin_amdgcn_sched_barrier(0);                       \
    } while (0)
#define ATT_BAR_VM0()                                            \
    do {                                                         \
        asm volatile("s_waitcnt vmcnt(0)" ::: "memory");         \
        __builtin_amdgcn_s_barrier();                            \
        __builtin_amdgcn_sched_barrier(0);                       \
    } while (0)

__global__ __launch_bounds__(256) void attn_k(const ushort* __restrict__ tmpb,
                                              const ushort* __restrict__ ckvb,
                                              const ushort* __restrict__ vtb,
                                              ushort* __restrict__ ctxb,
                                              int S, int T, int PAST) {
    __shared__ __align__(16) ushort buf[2][8192];  // K view: [64][128]; V view: [128][64]
    __shared__ __align__(16) ushort pl[4][16][72]; // per-wave P [q16][t64+8pad]
    const int tid = threadIdx.x, wid = tid >> 6, lane = tid & 63;
    const int h = blockIdx.y, b = blockIdx.z;
    const int s0 = ((int)gridDim.x - 1 - (int)blockIdx.x) * 64;  // longest-first

    bf16x8 qf[16];
    {
        const ushort* qb = tmpb + ((long)(b * HH + h) * S + s0 + wid * 16 + (lane & 15)) * LL +
                           ((lane >> 4) << 3);
#pragma unroll
        for (int ks = 0; ks < 16; ++ks) qf[ks] = *(const bf16x8*)(qb + ks * 32);
    }
    f32x4 cacc[8] = {};
    f32x4 sacc[4] = {};
    float mrow[4] = {-1e30f, -1e30f, -1e30f, -1e30f};
    float lrow[4] = {0.f, 0.f, 0.f, 0.f};
    const int rl = tid >> 4, cc16 = tid & 15;  // K staging coords (16 rows x 16 lanes)
    const int vr = tid >> 3, vc = tid & 7;     // V staging coords (32 rows x 8 lanes)
    const int q8 = (lane >> 4) << 3;
    const int l15 = lane & 15;
    const int swr = (l15 & 7) << 3;            // read-side XOR (ushort units)
    const int nfull = (s0 + PAST) / 64;
    const ushort* kbase = ckvb + (long)b * T * LL;
    const ushort* vbase = vtb + ((long)b * DV + h * DHD) * T;
    const int kcol = (cc16 ^ (rl & 7)) << 3;   // pre-swizzled K source column (ushorts)
    const int vcol = (vc ^ (vr & 7)) << 3;     // pre-swizzled V source column (ushorts)

    auto stageK = [&](int tt_, int c_, int bi) {
#pragma unroll
        for (int p = 0; p < 4; ++p)
            gll16(kbase + (long)(tt_ * 64 + p * 16 + rl) * LL + c_ * 128 + kcol,
                  &buf[bi][p * 2048 + tid * 8]);
    };
    auto stageV = [&](int tt_, int bi) {
#pragma unroll
        for (int p = 0; p < 4; ++p)
            gll16(vbase + (long)(p * 32 + vr) * T + tt_ * 64 + vcol,
                  &buf[bi][p * 2048 + tid * 8]);
    };

#define QK_CHUNK(C, BP)                                                                     \
    do {                                                                                    \
        __builtin_amdgcn_s_setprio(1);                                                      \
        _Pragma("unroll") for (int kk = 0; kk < 4; ++kk) {                                  \
            const int ko = kk * 32 + q8;                                                    \
            _Pragma("unroll") for (int nf = 0; nf < 4; ++nf) {                              \
                bf16x8 bfr = *(const bf16x8*)(&buf[BP][(nf * 16 + l15) * 128 + (ko ^ swr)]); \
                sacc[nf] = __builtin_amdgcn_mfma_f32_16x16x32_bf16(qf[(C)*4 + kk], bfr,     \
                                                                   sacc[nf], 0, 0, 0);      \
            }                                                                               \
        }                                                                                   \
        __builtin_amdgcn_s_setprio(0);                                                      \
    } while (0)

    // prologue: K(0,0)->buf0, K(0,1)->buf1; wait d(0); barrier
    stageK(0, 0, 0);
    stageK(0, 1, 1);
    ATT_BAR_VM4();

    for (int tt = 0; tt <= nfull; ++tt) {
        const int t0 = tt * 64;
        const bool partial = (tt == nfull);
        const int e = tt & 1, o = e ^ 1;
        // phase 0: QK chunk0 from buf[e]; then stage K(tt,2) into freed buf[e]
        QK_CHUNK(0, e);
        ATT_BAR_LG();
        stageK(tt, 2, e);
        ATT_BAR_VM4();
        // phase 1: QK chunk1 from buf[o]; stage K(tt,3) -> buf[o]
        QK_CHUNK(1, o);
        ATT_BAR_LG();
        stageK(tt, 3, o);
        ATT_BAR_VM4();
        // phase 2: QK chunk2 from buf[e]; stage V(tt) -> buf[e]
        QK_CHUNK(2, e);
        ATT_BAR_LG();
        stageV(tt, e);
        ATT_BAR_VM4();
        // phase 3: QK chunk3 from buf[o]; stage K(tt+1,0) -> buf[o]
        QK_CHUNK(3, o);
        ATT_BAR_LG();
        if (!partial) {
            stageK(tt + 1, 0, o);
            ATT_BAR_VM4();
        } else {
            ATT_BAR_VM0();
        }
        // phase 4: softmax + PV from buf[e] (V); stage K(tt+1,1) -> buf[e]
        float pm[4] = {-1e30f, -1e30f, -1e30f, -1e30f};
#pragma unroll
        for (int nf = 0; nf < 4; ++nf)
#pragma unroll
            for (int r = 0; r < 4; ++r) {
                float v = sacc[nf][r];
                if (partial) {
                    int tcol = nf * 16 + l15;
                    int qrl = wid * 16 + ((lane >> 4) << 2) + r;
                    if (tcol > qrl) v = -1e30f;
                }
                sacc[nf][r] = v;
                pm[r] = fmaxf(pm[r], v);
            }
#pragma unroll
        for (int r = 0; r < 4; ++r)
#pragma unroll
            for (int m = 1; m < 16; m <<= 1) pm[r] = fmaxf(pm[r], __shfl_xor(pm[r], m, 64));
        bool need = false;
#pragma unroll
        for (int r = 0; r < 4; ++r) need |= (pm[r] > mrow[r] + 8.0f);
        if (__any(need)) {
#pragma unroll
            for (int r = 0; r < 4; ++r) {
                float mn = fmaxf(mrow[r], pm[r]);
                float al = __expf(mrow[r] - mn);
                mrow[r] = mn;
                lrow[r] *= al;
#pragma unroll
                for (int df = 0; df < 8; ++df) cacc[df][r] *= al;
            }
        }
        float ps[4] = {0.f, 0.f, 0.f, 0.f};
#pragma unroll
        for (int nf = 0; nf < 4; ++nf)
#pragma unroll
            for (int r = 0; r < 4; ++r) {
                float p = __expf(sacc[nf][r] - mrow[r]);
                sacc[nf][r] = p;
                ps[r] += p;
            }
#pragma unroll
        for (int r = 0; r < 4; ++r) {
#pragma unroll
            for (int m = 1; m < 16; m <<= 1) ps[r] += __shfl_xor(ps[r], m, 64);
            lrow[r] += ps[r];
        }
        // P -> wave-private LDS
#pragma unroll
        for (int nf = 0; nf < 4; ++nf)
#pragma unroll
            for (int r = 0; r < 4; ++r)
                pl[wid][((lane >> 4) << 2) + r][nf * 16 + l15] = f2b(sacc[nf][r]);
#pragma unroll
        for (int nf = 0; nf < 4; ++nf) sacc[nf] = (f32x4){0.f, 0.f, 0.f, 0.f};
        // ctx += P * V  (V rows d = df*16+l15, swizzled cols)
        __builtin_amdgcn_s_setprio(1);
#pragma unroll
        for (int kk = 0; kk < 2; ++kk) {
            bf16x8 a = *(const bf16x8*)(&pl[wid][l15][kk * 32 + q8]);
#pragma unroll
            for (int df = 0; df < 8; ++df) {
                bf16x8 bv = *(const bf16x8*)(&buf[e][(df * 16 + l15) * 64 + ((kk * 32 + q8) ^ swr)]);
                cacc[df] = __builtin_amdgcn_mfma_f32_16x16x32_bf16(a, bv, cacc[df], 0, 0, 0);
            }
        }
        __builtin_amdgcn_s_setprio(0);
        if (!partial) {
            ATT_BAR_LG();
            stageK(tt + 1, 1, e);
            ATT_BAR_VM4();
        }
    }
    // ---- epilogue ----
    const long rbase = (long)b * S + s0 + wid * 16 + ((lane >> 4) << 2);
#pragma unroll
    for (int r = 0; r < 4; ++r) {
        float inv = 1.0f / lrow[r];
        const int d = h * DHD + l15;
#pragma unroll
        for (int df = 0; df < 8; ++df)
            ctxb[(rbase + r) * DV + d + df * 16] = f2b(cacc[df][r] * inv);
    }
}

extern "C" void kernel_launch(void* const* d_in, const int* in_sizes, int n_in,
                              void* d_out, int out_size, void* d_ws, size_t ws_size,
                              hipStream_t stream) {
    const float* x = (const float*)d_in[0];
    const float* kv = (const float*)d_in[1];
    const float* Wq = (const float*)d_in[2];
    const float* Wdkv = (const float*)d_in[3];
    const float* Wuk = (const float*)d_in[4];
    const float* Wuv = (const float*)d_in[5];
    const float* Wo = (const float*)d_in[6];
    const float* lng = (const float*)d_in[7];
    const float* lnbt = (const float*)d_in[8];
    const int S = in_sizes[0] / (BB * DV);     // 2048
    const int PAST = in_sizes[1] / (BB * LL);  // 2048
    const int T = S + PAST;                    // 4096

    float* out_p = (float*)d_out;                       // [B,S,D] f32
    float* ckv_out = out_p + (size_t)BB * S * DV;       // [B,T,L] f32

    char* w = (char*)d_ws;
    auto take = [&](size_t bytes) { char* p = w; w += (bytes + 255) & ~(size_t)255; return p; };
    ushort* xb    = (ushort*)take((size_t)BB * S * DV * 2);
    ushort* Wqb   = (ushort*)take((size_t)DV * DV * 2);
    ushort* WukT  = (ushort*)take((size_t)DV * LL * 2);   // [L][D]
    ushort* Wdkvb = (ushort*)take((size_t)LL * DV * 2);
    ushort* Wuvb  = (ushort*)take((size_t)DV * LL * 2);
    ushort* Wob   = (ushort*)take((size_t)DV * DV * 2);
    ushort* absT  = (ushort*)take((size_t)LL * DV * 2);   // [L][D] = absorbed^T
    float*  cpre  = (float*)take((size_t)BB * S * LL * 4);
    ushort* ckvb  = (ushort*)take((size_t)BB * T * LL * 2);
    ushort* vtb   = (ushort*)take((size_t)BB * DV * T * 2); // [B][D][T]
    ushort* tmpb  = (ushort*)take((size_t)BB * HH * S * LL * 2);
    ushort* ctxb  = (ushort*)take((size_t)BB * S * DV * 2);

    auto cvt = [&](const float* in, ushort* op, long n) {
        long nb = (n / 4 + 255) / 256;
        if (nb > 2048) nb = 2048;
        cvt_k<<<dim3((unsigned)nb), dim3(256), 0, stream>>>(in, op, n);
    };
    cvt(x, xb, (long)BB * S * DV);
    cvt(Wq, Wqb, (long)DV * DV);
    cvt(Wdkv, Wdkvb, (long)LL * DV);
    cvt(Wuv, Wuvb, (long)DV * LL);
    cvt(Wo, Wob, (long)DV * DV);
    transpose_cvt_k<<<dim3(LL / 64, DV / 64), dim3(256), 0, stream>>>(Wuk, WukT, DV, LL);
    kvcopy_k<<<dim3(2048), dim3(256), 0, stream>>>(kv, ckv_out, ckvb, PAST, T);

    // absorbed^T[l,i] = sum_k WukT[l,k] * Wq[i,k]
    gemm_nt<true><<<dim3(LL / 128, DV / 128, 1), dim3(256), 0, stream>>>(
        WukT, Wqb, absT, DV, DV, DV, DV, 0, 0, 0, 0, 0, 0, 1, 1.0f);
    // c_pre = x * Wdkv^T  (f32)
    gemm_nt<false><<<dim3(BB * S / 128, LL / 128, 1), dim3(256), 0, stream>>>(
        xb, Wdkvb, cpre, DV, DV, DV, LL, 0, 0, 0, 0, 0, 0, 1, 1.0f);
    ln_k<<<dim3(BB * S / 4), dim3(256), 0, stream>>>(cpre, lng, lnbt, ckv_out, ckvb, S, PAST, T);
    // Vt[b] = Wuv * ckv[b]^T : [D][T] bf16
    gemm_nt<true><<<dim3(DV / 128, T / 128, BB), dim3(256), 0, stream>>>(
        Wuvb, ckvb, vtb, LL, LL, LL, T, 0, 0, (long)T * LL, 0, (long)DV * T, 0, 1, 1.0f);
    // tmp[b,h] = x_h * absorbed_h^T, pre-scaled by 1/sqrt(dh)
    gemm_nt<true><<<dim3(S / 128, LL / 128, BB * HH), dim3(256), 0, stream>>>(
        xb, absT, tmpb, DHD, DV, DV, LL,
        (long)S * DV, DHD, 0, DHD, (long)HH * S * LL, (long)S * LL, HH,
        0.08838834764831845f);
    // attention
    attn_k<<<dim3(S / 64, HH, BB), dim3(256), 0, stream>>>(tmpb, ckvb, vtb, ctxb, S, T, PAST);
    // out = ctx * Wo^T (f32)
    gemm_nt<false><<<dim3(BB * S / 128, DV / 128, 1), dim3(256), 0, stream>>>(
        ctxb, Wob, out_p, DV, DV, DV, DV, 0, 0, 0, 0, 0, 0, 1, 1.0f);
}

// Round 5
// 795.525 us; speedup vs baseline: 1.5821x; 1.0359x over previous
//
#include <hip/hip_runtime.h>
#include <cstdint>

#define DV 2048
#define HH 16
#define DHD 128
#define LL 512
#define BB 2

typedef __attribute__((ext_vector_type(8))) short bf16x8;
typedef __attribute__((ext_vector_type(4))) float f32x4;
typedef __attribute__((ext_vector_type(4))) int i32x4;

typedef __attribute__((address_space(1))) const void* gas_cp;
typedef __attribute__((address_space(3))) void* las_p;

__device__ __forceinline__ void gll16(const void* g, void* l) {
    __builtin_amdgcn_global_load_lds((gas_cp)g, (las_p)l, 16, 0, 0);
}

__device__ __forceinline__ unsigned short f2b(float f) {
    union { float f; unsigned int u; } v; v.f = f;
    unsigned int u = v.u;
    return (unsigned short)((u + 0x7FFFu + ((u >> 16) & 1u)) >> 16);
}

// ---------------- elementwise f32 -> bf16 ----------------
__global__ void cvt_k(const float* __restrict__ in, ushort* __restrict__ out, long n) {
    long stride = (long)gridDim.x * blockDim.x * 4;
    for (long i = ((long)blockIdx.x * blockDim.x + threadIdx.x) * 4; i < n; i += stride) {
        float4 f = *(const float4*)(in + i);
        *(ushort4*)(out + i) = make_ushort4(f2b(f.x), f2b(f.y), f2b(f.z), f2b(f.w));
    }
}

// ---------------- transpose + convert: out[c][r] = in[r][c] ----------------
__global__ void transpose_cvt_k(const float* __restrict__ in, ushort* __restrict__ outp,
                                int R, int C) {
    __shared__ float tile[64][65];
    int c0 = blockIdx.x * 64, r0 = blockIdx.y * 64;
    int tx = threadIdx.x & 63, ty = threadIdx.x >> 6;
#pragma unroll
    for (int p = 0; p < 16; ++p)
        tile[ty + p * 4][tx] = in[(long)(r0 + ty + p * 4) * C + c0 + tx];
    __syncthreads();
#pragma unroll
    for (int p = 0; p < 16; ++p)
        outp[(long)(c0 + ty + p * 4) * R + r0 + tx] = f2b(tile[tx][ty + p * 4]);
}

// ---------------- kv_cache -> c_kv out (f32) + bf16 copy ----------------
__global__ void kvcopy_k(const float* __restrict__ kv, float* __restrict__ cko,
                         ushort* __restrict__ ckb, int PAST, int T) {
    long n = (long)BB * PAST * LL;
    long pl2 = (long)PAST * LL;
    long stride = (long)gridDim.x * blockDim.x * 4;
    for (long i = ((long)blockIdx.x * blockDim.x + threadIdx.x) * 4; i < n; i += stride) {
        float4 f = *(const float4*)(kv + i);
        long b = i / pl2, wloc = i - b * pl2;
        long o = b * (long)T * LL + wloc;
        *(float4*)(cko + o) = f;
        *(ushort4*)(ckb + o) = make_ushort4(f2b(f.x), f2b(f.y), f2b(f.z), f2b(f.w));
    }
}

// ---------------- LayerNorm over L=512, one wave per row ----------------
__global__ __launch_bounds__(256) void ln_k(const float* __restrict__ cpre,
                                            const float* __restrict__ g, const float* __restrict__ be,
                                            float* __restrict__ cko, ushort* __restrict__ ckb,
                                            int S, int PAST, int T) {
    int wid = threadIdx.x >> 6, lane = threadIdx.x & 63;
    int row = blockIdx.x * 4 + wid;
    int b = row / S, s = row - b * S;
    const float* xr = cpre + (long)row * LL + lane * 8;
    float4 v0 = *(const float4*)xr;
    float4 v1 = *(const float4*)(xr + 4);
    float sum = v0.x + v0.y + v0.z + v0.w + v1.x + v1.y + v1.z + v1.w;
    float sq = v0.x * v0.x + v0.y * v0.y + v0.z * v0.z + v0.w * v0.w +
               v1.x * v1.x + v1.y * v1.y + v1.z * v1.z + v1.w * v1.w;
#pragma unroll
    for (int m = 1; m < 64; m <<= 1) { sum += __shfl_xor(sum, m, 64); sq += __shfl_xor(sq, m, 64); }
    float mu = sum * (1.0f / LL);
    float var = sq * (1.0f / LL) - mu * mu;
    float rstd = rsqrtf(var + 1e-5f);
    const float* gp = g + lane * 8;
    const float* bp = be + lane * 8;
    float4 g0 = *(const float4*)gp, g1 = *(const float4*)(gp + 4);
    float4 b0 = *(const float4*)bp, b1 = *(const float4*)(bp + 4);
    float y0 = (v0.x - mu) * rstd * g0.x + b0.x;
    float y1 = (v0.y - mu) * rstd * g0.y + b0.y;
    float y2 = (v0.z - mu) * rstd * g0.z + b0.z;
    float y3 = (v0.w - mu) * rstd * g0.w + b0.w;
    float y4 = (v1.x - mu) * rstd * g1.x + b1.x;
    float y5 = (v1.y - mu) * rstd * g1.y + b1.y;
    float y6 = (v1.z - mu) * rstd * g1.z + b1.z;
    float y7 = (v1.w - mu) * rstd * g1.w + b1.w;
    long o = ((long)b * T + PAST + s) * LL + lane * 8;
    *(float4*)(cko + o) = make_float4(y0, y1, y2, y3);
    *(float4*)(cko + o + 4) = make_float4(y4, y5, y6, y7);
    *(ushort4*)(ckb + o) = make_ushort4(f2b(y0), f2b(y1), f2b(y2), f2b(y3));
    *(ushort4*)(ckb + o + 4) = make_ushort4(f2b(y4), f2b(y5), f2b(y6), f2b(y7));
}

// ---------------- generic NT GEMM: C[M,N] = cscale * A[M,K] * B[N,K]^T ----------------
template <bool OUT_BF16>
__global__ __launch_bounds__(256, 2) void gemm_nt(const ushort* __restrict__ A,
                                                  const ushort* __restrict__ B,
                                                  void* __restrict__ Cv,
                                                  int K, int lda, int ldb, int ldc,
                                                  long aHi, long aLo, long bHi, long bLo,
                                                  long cHi, long cLo, int zdiv, float cscale) {
    __shared__ __align__(16) ushort Asm[128 * 72];
    __shared__ __align__(16) ushort Bsm[128 * 72];
    const int tid = threadIdx.x, wid = tid >> 6, lane = tid & 63;
    const int z = blockIdx.z, zh = z / zdiv, zl = z % zdiv;
    A += zh * aHi + zl * aLo;
    B += zh * bHi + zl * bLo;
    const long cOff = zh * cHi + zl * cLo;
    const int m0 = blockIdx.x * 128, n0 = blockIdx.y * 128;
    const int wm = (wid >> 1) * 64, wn = (wid & 1) * 64;
    f32x4 acc[4][4] = {};
    const int l8 = lane & 7;
    const int rowA = wid * 8 + (lane >> 3);
    const ushort* Ag = A + (long)(m0 + rowA) * lda + l8 * 8;
    const ushort* Bg = B + (long)(n0 + rowA) * ldb + l8 * 8;

    i32x4 ra[4], rb[4];
#pragma unroll
    for (int p = 0; p < 4; ++p) {
        ra[p] = *(const i32x4*)(Ag + (long)p * 32 * lda);
        rb[p] = *(const i32x4*)(Bg + (long)p * 32 * ldb);
    }
    for (int kt = 0; kt < K; kt += 64) {
        __syncthreads();
#pragma unroll
        for (int p = 0; p < 4; ++p) {
            *(i32x4*)(Asm + (p * 32 + rowA) * 72 + l8 * 8) = ra[p];
            *(i32x4*)(Bsm + (p * 32 + rowA) * 72 + l8 * 8) = rb[p];
        }
        __syncthreads();
        if (kt + 64 < K) {
#pragma unroll
            for (int p = 0; p < 4; ++p) {
                ra[p] = *(const i32x4*)(Ag + (long)p * 32 * lda + kt + 64);
                rb[p] = *(const i32x4*)(Bg + (long)p * 32 * ldb + kt + 64);
            }
        }
#pragma unroll
        for (int kk = 0; kk < 2; ++kk) {
            const int ko = kk * 32 + ((lane >> 4) << 3);
            bf16x8 af[4], bf[4];
#pragma unroll
            for (int i = 0; i < 4; ++i)
                af[i] = *(const bf16x8*)(Asm + (wm + i * 16 + (lane & 15)) * 72 + ko);
#pragma unroll
            for (int j = 0; j < 4; ++j)
                bf[j] = *(const bf16x8*)(Bsm + (wn + j * 16 + (lane & 15)) * 72 + ko);
#pragma unroll
            for (int i = 0; i < 4; ++i)
#pragma unroll
                for (int j = 0; j < 4; ++j)
                    acc[i][j] = __builtin_amdgcn_mfma_f32_16x16x32_bf16(af[i], bf[j], acc[i][j], 0, 0, 0);
        }
        __syncthreads();
    }
    const int cr = (lane >> 4) * 4, cc = lane & 15;
#pragma unroll
    for (int i = 0; i < 4; ++i) {
#pragma unroll
        for (int r = 0; r < 4; ++r) {
            const long row = m0 + wm + i * 16 + cr + r;
#pragma unroll
            for (int j = 0; j < 4; ++j) {
                const long col = n0 + wn + j * 16 + cc;
                if (OUT_BF16)
                    ((ushort*)Cv)[cOff + row * ldc + col] = f2b(acc[i][j][r] * cscale);
                else
                    ((float*)Cv)[cOff + row * ldc + col] = acc[i][j][r] * cscale;
            }
        }
    }
}

// ---------------- flash attention (round 5) ----------------
// 4 waves x 16 q-rows. Staging stream per tile = [K0,K1,K2,K3,V] rotating
// through THREE 16 KB LDS buffers: ONE combined waitcnt+barrier per phase,
// loads issued 2 phases ahead (vmcnt(4) steady state, 0 only at the end).
#define PH_WAIT4()                                               \
    do {                                                         \
        asm volatile("s_waitcnt vmcnt(4) lgkmcnt(0)" ::: "memory"); \
        __builtin_amdgcn_s_barrier();                            \
    } while (0)
#define PH_WAIT0()                                               \
    do {                                                         \
        asm volatile("s_waitcnt vmcnt(0) lgkmcnt(0)" ::: "memory"); \
        __builtin_amdgcn_s_barrier();                            \
    } while (0)

__global__ __launch_bounds__(256) void attn_k(const ushort* __restrict__ tmpb,
                                              const ushort* __restrict__ ckvb,
                                              const ushort* __restrict__ vtb,
                                              ushort* __restrict__ ctxb,
                                              int S, int T, int PAST) {
    __shared__ __align__(16) ushort buf[3][8192];  // K view: [64][128]; V view: [128][64]
    __shared__ __align__(16) ushort pl[4][16][72]; // per-wave P [q16][t64+8pad]
    const int tid = threadIdx.x, wid = tid >> 6, lane = tid & 63;
    const int h = blockIdx.y, b = blockIdx.z;
    const int s0 = ((int)gridDim.x - 1 - (int)blockIdx.x) * 64;  // longest-first

    bf16x8 qf[16];
    {
        const ushort* qb = tmpb + ((long)(b * HH + h) * S + s0 + wid * 16 + (lane & 15)) * LL +
                           ((lane >> 4) << 3);
#pragma unroll
        for (int ks = 0; ks < 16; ++ks) qf[ks] = *(const bf16x8*)(qb + ks * 32);
    }
    f32x4 cacc[8] = {};
    f32x4 sacc[4] = {};
    float mrow[4] = {-1e30f, -1e30f, -1e30f, -1e30f};
    float lrow[4] = {0.f, 0.f, 0.f, 0.f};
    const int rl = tid >> 4, cc16 = tid & 15;  // K staging coords (16 rows x 16 lanes)
    const int vr = tid >> 3, vc = tid & 7;     // V staging coords (32 rows x 8 lanes)
    const int q8 = (lane >> 4) << 3;
    const int l15 = lane & 15;
    const int swr = (l15 & 7) << 3;            // read-side XOR (ushort units)
    const int nfull = (s0 + PAST) / 64;
    const ushort* kbase = ckvb + (long)b * T * LL;
    const ushort* vbase = vtb + ((long)b * DV + h * DHD) * T;
    const int kcol = (cc16 ^ (rl & 7)) << 3;   // pre-swizzled K source column (ushorts)
    const int vcol = (vc ^ (vr & 7)) << 3;     // pre-swizzled V source column (ushorts)

    auto stageK = [&](int tt_, int c_, int bi) {
#pragma unroll
        for (int p = 0; p < 4; ++p)
            gll16(kbase + (long)(tt_ * 64 + p * 16 + rl) * LL + c_ * 128 + kcol,
                  &buf[bi][p * 2048 + tid * 8]);
    };
    auto stageV = [&](int tt_, int bi) {
#pragma unroll
        for (int p = 0; p < 4; ++p)
            gll16(vbase + (long)(p * 32 + vr) * T + tt_ * 64 + vcol,
                  &buf[bi][p * 2048 + tid * 8]);
    };

#define QK_CHUNK(C, BP)                                                                      \
    do {                                                                                     \
        const ushort* kb_ = &buf[BP][0];                                                     \
        __builtin_amdgcn_s_setprio(1);                                                       \
        _Pragma("unroll") for (int kk = 0; kk < 4; ++kk) {                                   \
            const int ko = kk * 32 + q8;                                                     \
            _Pragma("unroll") for (int nf = 0; nf < 4; ++nf) {                               \
                bf16x8 bfr = *(const bf16x8*)(&kb_[(nf * 16 + l15) * 128 + (ko ^ swr)]);     \
                sacc[nf] = __builtin_amdgcn_mfma_f32_16x16x32_bf16(qf[(C)*4 + kk], bfr,      \
                                                                   sacc[nf], 0, 0, 0);       \
            }                                                                                \
        }                                                                                    \
        __builtin_amdgcn_s_setprio(0);                                                       \
    } while (0)

    // prologue: stream items 0,1 = K(0,0)->buf0, K(0,1)->buf1
    stageK(0, 0, 0);
    stageK(0, 1, 1);
    int bi0 = 0;  // buffer index of this tile's item c=0

    for (int tt = 0; tt <= nfull; ++tt) {
        const int t0 = tt * 64;
        const bool last = (tt == nfull);
        // buffer indices for phases c=0..4 (bi0 + c mod 3)
        int bA = bi0;                       // c=0 consume
        int bB = bi0 + 1; if (bB >= 3) bB -= 3;  // c=1 consume / c=4 consume (V)
        int bC = bi0 + 2; if (bC >= 3) bC -= 3;  // c=2 consume / c=0 stage target
        // phase 0: consume K0 from bA; stage K(tt,2) -> bC
        PH_WAIT4();
        stageK(tt, 2, bC);
        QK_CHUNK(0, bA);
        // phase 1: consume K1 from bB; stage K(tt,3) -> bA
        PH_WAIT4();
        stageK(tt, 3, bA);
        QK_CHUNK(1, bB);
        // phase 2: consume K2 from bC; stage V(tt) -> bB
        PH_WAIT4();
        stageV(tt, bB);
        QK_CHUNK(2, bC);
        // phase 3: consume K3 from bA; stage K(tt+1,0) -> bC
        PH_WAIT4();
        if (!last) stageK(tt + 1, 0, bC);
        QK_CHUNK(3, bA);
        // phase 4: consume V from bB; stage K(tt+1,1) -> bA
        if (last) { PH_WAIT0(); } else { PH_WAIT4(); }
        if (!last) stageK(tt + 1, 1, bA);
        // ---- online softmax (scores pre-scaled in tmp GEMM) ----
        float pm[4] = {-1e30f, -1e30f, -1e30f, -1e30f};
#pragma unroll
        for (int nf = 0; nf < 4; ++nf)
#pragma unroll
            for (int r = 0; r < 4; ++r) {
                float v = sacc[nf][r];
                if (last) {
                    int tcol = nf * 16 + l15;
                    int qrl = wid * 16 + ((lane >> 4) << 2) + r;
                    if (tcol > qrl) v = -1e30f;
                }
                sacc[nf][r] = v;
                pm[r] = fmaxf(pm[r], v);
            }
#pragma unroll
        for (int r = 0; r < 4; ++r)
#pragma unroll
            for (int m = 1; m < 16; m <<= 1) pm[r] = fmaxf(pm[r], __shfl_xor(pm[r], m, 64));
        bool need = false;
#pragma unroll
        for (int r = 0; r < 4; ++r) need |= (pm[r] > mrow[r] + 8.0f);
        if (__any(need)) {
#pragma unroll
            for (int r = 0; r < 4; ++r) {
                float mn = fmaxf(mrow[r], pm[r]);
                float al = __expf(mrow[r] - mn);
                mrow[r] = mn;
                lrow[r] *= al;
#pragma unroll
                for (int df = 0; df < 8; ++df) cacc[df][r] *= al;
            }
        }
        float ps[4] = {0.f, 0.f, 0.f, 0.f};
#pragma unroll
        for (int nf = 0; nf < 4; ++nf)
#pragma unroll
            for (int r = 0; r < 4; ++r) {
                float p = __expf(sacc[nf][r] - mrow[r]);
                sacc[nf][r] = p;
                ps[r] += p;
            }
#pragma unroll
        for (int r = 0; r < 4; ++r) {
#pragma unroll
            for (int m = 1; m < 16; m <<= 1) ps[r] += __shfl_xor(ps[r], m, 64);
            lrow[r] += ps[r];
        }
        // P -> wave-private LDS
#pragma unroll
        for (int nf = 0; nf < 4; ++nf)
#pragma unroll
            for (int r = 0; r < 4; ++r)
                pl[wid][((lane >> 4) << 2) + r][nf * 16 + l15] = f2b(sacc[nf][r]);
#pragma unroll
        for (int nf = 0; nf < 4; ++nf) sacc[nf] = (f32x4){0.f, 0.f, 0.f, 0.f};
        // ctx += P * V from bB (V rows d = df*16+l15, swizzled cols)
        {
            const ushort* vb_ = &buf[bB][0];
            __builtin_amdgcn_s_setprio(1);
#pragma unroll
            for (int kk = 0; kk < 2; ++kk) {
                bf16x8 a = *(const bf16x8*)(&pl[wid][l15][kk * 32 + q8]);
#pragma unroll
                for (int df = 0; df < 8; ++df) {
                    bf16x8 bv = *(const bf16x8*)(&vb_[(df * 16 + l15) * 64 + ((kk * 32 + q8) ^ swr)]);
                    cacc[df] = __builtin_amdgcn_mfma_f32_16x16x32_bf16(a, bv, cacc[df], 0, 0, 0);
                }
            }
            __builtin_amdgcn_s_setprio(0);
        }
        // advance rotation: next tile's c=0 item sits at bi0+5 mod 3 = bi0+2 mod 3
        bi0 = bC;
    }
    // ---- epilogue ----
    const long rbase = (long)b * S + s0 + wid * 16 + ((lane >> 4) << 2);
#pragma unroll
    for (int r = 0; r < 4; ++r) {
        float inv = 1.0f / lrow[r];
        const int d = h * DHD + l15;
#pragma unroll
        for (int df = 0; df < 8; ++df)
            ctxb[(rbase + r) * DV + d + df * 16] = f2b(cacc[df][r] * inv);
    }
}

extern "C" void kernel_launch(void* const* d_in, const int* in_sizes, int n_in,
                              void* d_out, int out_size, void* d_ws, size_t ws_size,
                              hipStream_t stream) {
    const float* x = (const float*)d_in[0];
    const float* kv = (const float*)d_in[1];
    const float* Wq = (const float*)d_in[2];
    const float* Wdkv = (const float*)d_in[3];
    const float* Wuk = (const float*)d_in[4];
    const float* Wuv = (const float*)d_in[5];
    const float* Wo = (const float*)d_in[6];
    const float* lng = (const float*)d_in[7];
    const float* lnbt = (const float*)d_in[8];
    const int S = in_sizes[0] / (BB * DV);     // 2048
    const int PAST = in_sizes[1] / (BB * LL);  // 2048
    const int T = S + PAST;                    // 4096

    float* out_p = (float*)d_out;                       // [B,S,D] f32
    float* ckv_out = out_p + (size_t)BB * S * DV;       // [B,T,L] f32

    char* w = (char*)d_ws;
    auto take = [&](size_t bytes) { char* p = w; w += (bytes + 255) & ~(size_t)255; return p; };
    ushort* xb    = (ushort*)take((size_t)BB * S * DV * 2);
    ushort* Wqb   = (ushort*)take((size_t)DV * DV * 2);
    ushort* WukT  = (ushort*)take((size_t)DV * LL * 2);   // [L][D]
    ushort* Wdkvb = (ushort*)take((size_t)LL * DV * 2);
    ushort* Wuvb  = (ushort*)take((size_t)DV * LL * 2);
    ushort* Wob   = (ushort*)take((size_t)DV * DV * 2);
    ushort* absT  = (ushort*)take((size_t)LL * DV * 2);   // [L][D] = absorbed^T
    float*  cpre  = (float*)take((size_t)BB * S * LL * 4);
    ushort* ckvb  = (ushort*)take((size_t)BB * T * LL * 2);
    ushort* vtb   = (ushort*)take((size_t)BB * DV * T * 2); // [B][D][T]
    ushort* tmpb  = (ushort*)take((size_t)BB * HH * S * LL * 2);
    ushort* ctxb  = (ushort*)take((size_t)BB * S * DV * 2);

    auto cvt = [&](const float* in, ushort* op, long n) {
        long nb = (n / 4 + 255) / 256;
        if (nb > 2048) nb = 2048;
        cvt_k<<<dim3((unsigned)nb), dim3(256), 0, stream>>>(in, op, n);
    };
    cvt(x, xb, (long)BB * S * DV);
    cvt(Wq, Wqb, (long)DV * DV);
    cvt(Wdkv, Wdkvb, (long)LL * DV);
    cvt(Wuv, Wuvb, (long)DV * LL);
    cvt(Wo, Wob, (long)DV * DV);
    transpose_cvt_k<<<dim3(LL / 64, DV / 64), dim3(256), 0, stream>>>(Wuk, WukT, DV, LL);
    kvcopy_k<<<dim3(2048), dim3(256), 0, stream>>>(kv, ckv_out, ckvb, PAST, T);

    // absorbed^T[l,i] = sum_k WukT[l,k] * Wq[i,k]
    gemm_nt<true><<<dim3(LL / 128, DV / 128, 1), dim3(256), 0, stream>>>(
        WukT, Wqb, absT, DV, DV, DV, DV, 0, 0, 0, 0, 0, 0, 1, 1.0f);
    // c_pre = x * Wdkv^T  (f32)
    gemm_nt<false><<<dim3(BB * S / 128, LL / 128, 1), dim3(256), 0, stream>>>(
        xb, Wdkvb, cpre, DV, DV, DV, LL, 0, 0, 0, 0, 0, 0, 1, 1.0f);
    ln_k<<<dim3(BB * S / 4), dim3(256), 0, stream>>>(cpre, lng, lnbt, ckv_out, ckvb, S, PAST, T);
    // Vt[b] = Wuv * ckv[b]^T : [D][T] bf16
    gemm_nt<true><<<dim3(DV / 128, T / 128, BB), dim3(256), 0, stream>>>(
        Wuvb, ckvb, vtb, LL, LL, LL, T, 0, 0, (long)T * LL, 0, (long)DV * T, 0, 1, 1.0f);
    // tmp[b,h] = x_h * absorbed_h^T, pre-scaled by 1/sqrt(dh)
    gemm_nt<true><<<dim3(S / 128, LL / 128, BB * HH), dim3(256), 0, stream>>>(
        xb, absT, tmpb, DHD, DV, DV, LL,
        (long)S * DV, DHD, 0, DHD, (long)HH * S * LL, (long)S * LL, HH,
        0.08838834764831845f);
    // attention
    attn_k<<<dim3(S / 64, HH, BB), dim3(256), 0, stream>>>(tmpb, ckvb, vtb, ctxb, S, T, PAST);
    // out = ctx * Wo^T (f32)
    gemm_nt<false><<<dim3(BB * S / 128, DV / 128, 1), dim3(256), 0, stream>>>(
        ctxb, Wob, out_p, DV, DV, DV, DV, 0, 0, 0, 0, 0, 0, 1, 1.0f);
}